// Round 7
// baseline (449.337 us; speedup 1.0000x reference)
//
#include <hip/hip_runtime.h>
#include <math.h>

#define N_NODES 32768
#define N_FEAT 256
#define HID 256
#define N_GRAPHS 64
#define NPG 512
#define N_CLASSES 4
#define BN_EPS 1e-5f

typedef __attribute__((ext_vector_type(8))) short bf16x8;
typedef __attribute__((ext_vector_type(4))) float f32x4;

__device__ __forceinline__ ushort f2b(float f) {
    union { float f; uint u; } v; v.f = f;
    uint u = v.u;
    return (ushort)((u + 0x7FFFu + ((u >> 16) & 1u)) >> 16);   // RNE
}
__device__ __forceinline__ float bflo(uint u) {
    union { uint u; float f; } v; v.u = u << 16;
    return v.f;
}
__device__ __forceinline__ float bfhi(uint u) {
    union { uint u; float f; } v; v.u = u & 0xFFFF0000u;
    return v.f;
}

// ---------------- degree (int) ----------------
__global__ void k_count(const int* __restrict__ dst, int* __restrict__ degcnt, int E) {
    int e = blockIdx.x * 256 + threadIdx.x;
    if (e < E) atomicAdd(&degcnt[dst[e]], 1);
}

// single block (1024 thr): scan degcnt -> row_start/cursor (+sentinel), dinv = rsqrt(cnt+1)
__global__ __launch_bounds__(1024) void k_scan_all(const int* __restrict__ degcnt,
                                                   float* __restrict__ dinv,
                                                   int* __restrict__ row_start,
                                                   int* __restrict__ cursor) {
    __shared__ int wsum[16];
    int t = threadIdx.x;
    int base = t * 32;
    int s = 0;
#pragma unroll
    for (int i = 0; i < 32; ++i) s += degcnt[base + i];
    int lane = t & 63, w = t >> 6;
    int v = s;
    for (int off = 1; off < 64; off <<= 1) {
        int u = __shfl_up(v, off);
        if (lane >= off) v += u;
    }
    if (lane == 63) wsum[w] = v;
    __syncthreads();
    if (t < 16) {
        int x = wsum[t];
        for (int off = 1; off < 16; off <<= 1) {
            int u = __shfl_up(x, off, 16);
            if (t >= off) x += u;
        }
        wsum[t] = x;
    }
    __syncthreads();
    int run = ((w > 0) ? wsum[w - 1] : 0) + v - s;
    for (int i = 0; i < 32; ++i) {
        int n = base + i;
        int c = degcnt[n];
        row_start[n] = run;
        cursor[n] = run;
        dinv[n] = rsqrtf((float)(c + 1));
        run += c;
    }
    if (t == 0) row_start[N_NODES] = wsum[15];   // sentinel = E
}

// fill CSR with src only
__global__ void k_fill(const int* __restrict__ src, const int* __restrict__ dst,
                       int* __restrict__ cursor, uint* __restrict__ csrs, int E) {
    int e = blockIdx.x * 256 + threadIdx.x;
    if (e >= E) return;
    int d = dst[e];
    int pos = atomicAdd(&cursor[d], 1);
    csrs[pos] = (uint)src[e];
}

// ---------------- prep: x->bf16 + W transpose ----------------
__global__ void k_prep(const float* __restrict__ x, ushort* __restrict__ xb, int n8blk,
                       const float* __restrict__ W1, const float* __restrict__ W2,
                       ushort* __restrict__ Wt1, ushort* __restrict__ Wt2) {
    int b = blockIdx.x;
    if (b < n8blk) {
        int i = b * 256 + threadIdx.x;
        float4 v0 = *(const float4*)(x + (size_t)i * 8);
        float4 v1 = *(const float4*)(x + (size_t)i * 8 + 4);
        uint4 o;
        o.x = (uint)f2b(v0.x) | ((uint)f2b(v0.y) << 16);
        o.y = (uint)f2b(v0.z) | ((uint)f2b(v0.w) << 16);
        o.z = (uint)f2b(v1.x) | ((uint)f2b(v1.y) << 16);
        o.w = (uint)f2b(v1.z) | ((uint)f2b(v1.w) << 16);
        *(uint4*)(xb + (size_t)i * 8) = o;
    } else {
        int wb = b - n8blk;
        const float* W = (wb < 256) ? W1 : W2;
        ushort* Wt = (wb < 256) ? Wt1 : Wt2;
        int n = wb & 255;
        int k = threadIdx.x;
        Wt[n * 256 + k] = f2b(W[k * 256 + n]);
    }
}

// ---------------- bf16 MFMA GEMM: hs[row][256] = dinv[row] * (A @ Bt^T) ----------------
__global__ __launch_bounds__(256) void k_gemm_bf16(const ushort* __restrict__ A,
                                                   const ushort* __restrict__ Bt,
                                                   const float* __restrict__ dinv,
                                                   ushort* __restrict__ hs) {
    int wid = threadIdx.x >> 6;
    int lane = threadIdx.x & 63;
    int m0 = blockIdx.y * 256 + wid * 64;
    int n0 = blockIdx.x * 64;
    int r = lane & 15;
    int ko = (lane >> 4) * 8;

    const ushort* Ab = A + (size_t)(m0 + r) * 256 + ko;
    const ushort* Bb = Bt + (size_t)(n0 + r) * 256 + ko;

    f32x4 acc[4][4] = {};
#pragma unroll
    for (int ks = 0; ks < 8; ++ks) {
        bf16x8 a[4], b[4];
#pragma unroll
        for (int i = 0; i < 4; ++i) {
            a[i] = *(const bf16x8*)(Ab + i * (16 * 256) + ks * 32);
            b[i] = *(const bf16x8*)(Bb + i * (16 * 256) + ks * 32);
        }
#pragma unroll
        for (int i = 0; i < 4; ++i)
#pragma unroll
            for (int j = 0; j < 4; ++j)
                acc[i][j] = __builtin_amdgcn_mfma_f32_16x16x32_bf16(a[i], b[j], acc[i][j], 0, 0, 0);
    }

    int rr = (lane >> 4) * 4;   // C/D: row=(lane>>4)*4+reg, col=lane&15
    int cc = lane & 15;
#pragma unroll
    for (int i = 0; i < 4; ++i) {
        int row = m0 + i * 16 + rr;
#pragma unroll
        for (int r2 = 0; r2 < 4; ++r2) {
            float dv = dinv[row + r2];
#pragma unroll
            for (int j = 0; j < 4; ++j) {
                int col = n0 + j * 16 + cc;
                hs[(size_t)(row + r2) * 256 + col] = f2b(acc[i][j][r2] * dv);
            }
        }
    }
}

// ---------------- CSR aggregate + fused BN stats (full-row gather) ----------------
// hs[node][256] = dinv-prescaled h'. agg[n] = dv*(sum h'[src] + h'[n]) + bias.
// One wave per node (4 waves/block, 8 nodes each sequentially);
// lane owns feature quad f = lane*4 (uint2 = 4 bf16 per row-load). No shfl.
__global__ __launch_bounds__(256) void k_agg_bn(const ushort* __restrict__ hs,
                                                const uint* __restrict__ csrs,
                                                const int* __restrict__ row_start,
                                                const float* __restrict__ dinv,
                                                const float* __restrict__ bias,
                                                ushort* __restrict__ aggb,
                                                float* __restrict__ bnsum,
                                                float* __restrict__ bnsq) {
    int wid = threadIdx.x >> 6;
    int lane = threadIdx.x & 63;
    int foff = lane * 4;

    float4 bv = *(const float4*)&bias[foff];
    float bb[4] = {bv.x, bv.y, bv.z, bv.w};

    float s[4] = {0.f, 0.f, 0.f, 0.f};
    float q[4] = {0.f, 0.f, 0.f, 0.f};

    for (int t = 0; t < 8; ++t) {
        int n = blockIdx.x * 32 + wid * 8 + t;
        float dv = dinv[n];
        int base = row_start[n];
        int cnt = row_start[n + 1] - base;

        uint2 hv = *(const uint2*)(hs + (size_t)n * 256 + foff);
        float a0 = bflo(hv.x), a1 = bfhi(hv.x), a2 = bflo(hv.y), a3 = bfhi(hv.y);

        int j = 0;
        for (; j + 8 <= cnt; j += 8) {
            uint s0 = csrs[base + j + 0];
            uint s1 = csrs[base + j + 1];
            uint s2 = csrs[base + j + 2];
            uint s3 = csrs[base + j + 3];
            uint s4 = csrs[base + j + 4];
            uint s5 = csrs[base + j + 5];
            uint s6 = csrs[base + j + 6];
            uint s7 = csrs[base + j + 7];
            uint2 h0 = *(const uint2*)(hs + (size_t)s0 * 256 + foff);
            uint2 h1 = *(const uint2*)(hs + (size_t)s1 * 256 + foff);
            uint2 h2 = *(const uint2*)(hs + (size_t)s2 * 256 + foff);
            uint2 h3 = *(const uint2*)(hs + (size_t)s3 * 256 + foff);
            uint2 h4 = *(const uint2*)(hs + (size_t)s4 * 256 + foff);
            uint2 h5 = *(const uint2*)(hs + (size_t)s5 * 256 + foff);
            uint2 h6 = *(const uint2*)(hs + (size_t)s6 * 256 + foff);
            uint2 h7 = *(const uint2*)(hs + (size_t)s7 * 256 + foff);
            a0 += bflo(h0.x) + bflo(h1.x) + bflo(h2.x) + bflo(h3.x)
                + bflo(h4.x) + bflo(h5.x) + bflo(h6.x) + bflo(h7.x);
            a1 += bfhi(h0.x) + bfhi(h1.x) + bfhi(h2.x) + bfhi(h3.x)
                + bfhi(h4.x) + bfhi(h5.x) + bfhi(h6.x) + bfhi(h7.x);
            a2 += bflo(h0.y) + bflo(h1.y) + bflo(h2.y) + bflo(h3.y)
                + bflo(h4.y) + bflo(h5.y) + bflo(h6.y) + bflo(h7.y);
            a3 += bfhi(h0.y) + bfhi(h1.y) + bfhi(h2.y) + bfhi(h3.y)
                + bfhi(h4.y) + bfhi(h5.y) + bfhi(h6.y) + bfhi(h7.y);
        }
        for (; j + 4 <= cnt; j += 4) {
            uint s0 = csrs[base + j + 0];
            uint s1 = csrs[base + j + 1];
            uint s2 = csrs[base + j + 2];
            uint s3 = csrs[base + j + 3];
            uint2 h0 = *(const uint2*)(hs + (size_t)s0 * 256 + foff);
            uint2 h1 = *(const uint2*)(hs + (size_t)s1 * 256 + foff);
            uint2 h2 = *(const uint2*)(hs + (size_t)s2 * 256 + foff);
            uint2 h3 = *(const uint2*)(hs + (size_t)s3 * 256 + foff);
            a0 += bflo(h0.x) + bflo(h1.x) + bflo(h2.x) + bflo(h3.x);
            a1 += bfhi(h0.x) + bfhi(h1.x) + bfhi(h2.x) + bfhi(h3.x);
            a2 += bflo(h0.y) + bflo(h1.y) + bflo(h2.y) + bflo(h3.y);
            a3 += bfhi(h0.y) + bfhi(h1.y) + bfhi(h2.y) + bfhi(h3.y);
        }
        for (; j < cnt; ++j) {
            uint s0 = csrs[base + j];
            uint2 h0 = *(const uint2*)(hs + (size_t)s0 * 256 + foff);
            a0 += bflo(h0.x); a1 += bfhi(h0.x);
            a2 += bflo(h0.y); a3 += bfhi(h0.y);
        }

        float o0 = a0 * dv + bb[0];
        float o1 = a1 * dv + bb[1];
        float o2 = a2 * dv + bb[2];
        float o3 = a3 * dv + bb[3];
        ushort4 ov;
        ov.x = f2b(o0); ov.y = f2b(o1); ov.z = f2b(o2); ov.w = f2b(o3);
        *(ushort4*)(aggb + (size_t)n * HID + foff) = ov;
        s[0] += o0; q[0] += o0 * o0;
        s[1] += o1; q[1] += o1 * o1;
        s[2] += o2; q[2] += o2 * o2;
        s[3] += o3; q[3] += o3 * o3;
    }

    __shared__ float4 ssum[4][64];
    __shared__ float4 ssq[4][64];
    ssum[wid][lane] = make_float4(s[0], s[1], s[2], s[3]);
    ssq[wid][lane] = make_float4(q[0], q[1], q[2], q[3]);
    __syncthreads();
    if (threadIdx.x < 64) {
        float4 A = ssum[0][lane], B = ssq[0][lane];
#pragma unroll
        for (int w = 1; w < 4; ++w) {
            float4 a2v = ssum[w][lane], b2v = ssq[w][lane];
            A.x += a2v.x; A.y += a2v.y; A.z += a2v.z; A.w += a2v.w;
            B.x += b2v.x; B.y += b2v.y; B.z += b2v.z; B.w += b2v.w;
        }
        atomicAdd(&bnsum[foff + 0], A.x); atomicAdd(&bnsq[foff + 0], B.x);
        atomicAdd(&bnsum[foff + 1], A.y); atomicAdd(&bnsq[foff + 1], B.y);
        atomicAdd(&bnsum[foff + 2], A.z); atomicAdd(&bnsq[foff + 2], B.z);
        atomicAdd(&bnsum[foff + 3], A.w); atomicAdd(&bnsq[foff + 3], B.w);
    }
}

// ---------------- BN apply (layer1): aggb bf16 -> bf16 xb ----------------
__global__ void k_bn_apply_b(const ushort* __restrict__ x, const float* __restrict__ bnsum,
                             const float* __restrict__ bnsq, const float* __restrict__ gamma,
                             const float* __restrict__ beta, ushort* __restrict__ out) {
    int i = blockIdx.x * 256 + threadIdx.x;   // 4-feat groups
    if (i >= N_NODES * HID / 4) return;
    int f = (i & 63) * 4;
    const float invN = 1.0f / (float)N_NODES;
    uint2 v = *(const uint2*)(x + (size_t)i * 4);
    float vv[4] = {bflo(v.x), bfhi(v.x), bflo(v.y), bfhi(v.y)};
    float r[4];
#pragma unroll
    for (int qq = 0; qq < 4; ++qq) {
        float mean = bnsum[f + qq] * invN;
        float var = bnsq[f + qq] * invN - mean * mean;
        float t = (vv[qq] - mean) * rsqrtf(var + BN_EPS) * gamma[f + qq] + beta[f + qq];
        r[qq] = t > 0.0f ? t : 0.0f;
    }
    uint2 o;
    o.x = (uint)f2b(r[0]) | ((uint)f2b(r[1]) << 16);
    o.y = (uint)f2b(r[2]) | ((uint)f2b(r[3]) << 16);
    *(uint2*)(out + (size_t)i * 4) = o;
}

// ---------------- BN apply (layer2) + mean-pool accumulate (bf16 in) ----------------
__global__ __launch_bounds__(256) void k_bn_pool(const ushort* __restrict__ aggb,
                                                 const float* __restrict__ bnsum,
                                                 const float* __restrict__ bnsq,
                                                 const float* __restrict__ gamma,
                                                 const float* __restrict__ beta,
                                                 float* __restrict__ pooled) {
    int g = blockIdx.x >> 4;
    int blk = blockIdx.x & 15;
    int f = threadIdx.x;
    const float invN = 1.0f / (float)N_NODES;
    float mean = bnsum[f] * invN;
    float var = bnsq[f] * invN - mean * mean;
    float sc = rsqrtf(var + BN_EPS) * gamma[f];
    float sh = beta[f] - mean * sc;
    int r0 = g * NPG + blk * 32;
    float s = 0.0f;
#pragma unroll 4
    for (int r = 0; r < 32; ++r) {
        float v = bflo((uint)aggb[(size_t)(r0 + r) * HID + f]) * sc + sh;
        s += v > 0.0f ? v : 0.0f;
    }
    atomicAdd(&pooled[g * HID + f], s);
}

// ---------------- LSTM cell + FC + log_softmax ----------------
__global__ __launch_bounds__(256) void k_head(const float* __restrict__ pooled,
                                              const float* __restrict__ W_ih,
                                              const float* __restrict__ b_ih,
                                              const float* __restrict__ b_hh,
                                              const float* __restrict__ W_fc,
                                              const float* __restrict__ b_fc,
                                              float* __restrict__ out) {
    __shared__ float p[HID];
    __shared__ float lsum[N_CLASSES][256];
    __shared__ float logits[N_CLASSES];
    int g = blockIdx.x, j = threadIdx.x;
    p[j] = pooled[g * HID + j] * (1.0f / (float)NPG);
    __syncthreads();

    float gi = 0.f, gf = 0.f, gg = 0.f, go = 0.f;
#pragma unroll 4
    for (int k = 0; k < HID; ++k) {
        float pk = p[k];
        const float* w = &W_ih[(size_t)k * (4 * HID) + j];
        gi += pk * w[0];
        gf += pk * w[HID];
        gg += pk * w[2 * HID];
        go += pk * w[3 * HID];
    }
    gi += b_ih[j] + b_hh[j];
    gf += b_ih[HID + j] + b_hh[HID + j];
    gg += b_ih[2 * HID + j] + b_hh[2 * HID + j];
    go += b_ih[3 * HID + j] + b_hh[3 * HID + j];
    (void)gf;  // c0 == 0

    float si = 1.f / (1.f + expf(-gi));
    float so = 1.f / (1.f + expf(-go));
    float c1 = si * tanhf(gg);
    float h1 = so * tanhf(c1);

    out[N_GRAPHS * N_CLASSES + g * HID + j] = h1;
    out[N_GRAPHS * N_CLASSES + N_GRAPHS * HID + g * HID + j] = c1;

#pragma unroll
    for (int c = 0; c < N_CLASSES; ++c)
        lsum[c][j] = h1 * W_fc[j * N_CLASSES + c];
    __syncthreads();
    for (int s = 128; s > 0; s >>= 1) {
        if (j < s) {
#pragma unroll
            for (int c = 0; c < N_CLASSES; ++c)
                lsum[c][j] += lsum[c][j + s];
        }
        __syncthreads();
    }
    if (j < N_CLASSES) logits[j] = lsum[j][0] + b_fc[j];
    __syncthreads();
    if (j < N_CLASSES) {
        float m = fmaxf(fmaxf(logits[0], logits[1]), fmaxf(logits[2], logits[3]));
        float lse = m + logf(expf(logits[0] - m) + expf(logits[1] - m) +
                             expf(logits[2] - m) + expf(logits[3] - m));
        out[g * N_CLASSES + j] = logits[j] - lse;
    }
}

extern "C" void kernel_launch(void* const* d_in, const int* in_sizes, int n_in,
                              void* d_out, int out_size, void* d_ws, size_t ws_size,
                              hipStream_t stream) {
    const float* x    = (const float*)d_in[0];
    const int*   ei   = (const int*)d_in[1];
    const float* W1   = (const float*)d_in[3];
    const float* b1   = (const float*)d_in[4];
    const float* g1   = (const float*)d_in[5];
    const float* be1  = (const float*)d_in[6];
    const float* W2   = (const float*)d_in[7];
    const float* b2   = (const float*)d_in[8];
    const float* g2   = (const float*)d_in[9];
    const float* be2  = (const float*)d_in[10];
    const float* W_ih = (const float*)d_in[11];
    const float* b_ih = (const float*)d_in[13];
    const float* b_hh = (const float*)d_in[14];
    const float* W_fc = (const float*)d_in[15];
    const float* b_fc = (const float*)d_in[16];
    float* out = (float*)d_out;

    int E = in_sizes[1] / 2;
    const int* src = ei;
    const int* dst = ei + E;

    const size_t MAT = (size_t)N_NODES * HID;   // 8388608
    ushort* aggb = (ushort*)d_ws;               // bf16 aggregate output
    ushort* xb   = aggb + MAT;
    ushort* hs   = xb + MAT;                    // node-major prescaled GEMM output
    ushort* Wt1  = hs + MAT;
    ushort* Wt2  = Wt1 + 65536;
    float*  dinv = (float*)(Wt2 + 65536);
    int*    row_start = (int*)(dinv + N_NODES);           // N_NODES+1 (sentinel)
    int*    cursor    = row_start + N_NODES + 1;
    uint*   csrs      = (uint*)(cursor + N_NODES);        // E uints
    // zero-init region (one memset): degcnt + bn sums + pooled
    int*    degcnt = (int*)(csrs + E);
    float*  bn1sum = (float*)(degcnt + N_NODES);
    float*  bn1sq  = bn1sum + HID;
    float*  bn2sum = bn1sq + HID;
    float*  bn2sq  = bn2sum + HID;
    float*  pooled = bn2sq + HID;
    size_t zeroBytes = (size_t)N_NODES * 4 + 4 * HID * 4 + (size_t)N_GRAPHS * HID * 4;

    dim3 blk(256);
    int edgeBlocks = (E + 255) / 256;
    int n8blk = (int)(MAT / 8 / 256);           // 4096
    int vec4Blocks = (int)(MAT / 4 / 256);      // 8192
    int aggBlocks = N_NODES / 32;               // 1024
    dim3 gemmGrid(HID / 64, N_NODES / 256);

    hipMemsetAsync(degcnt, 0, zeroBytes, stream);

    // graph structure + prep
    k_count<<<edgeBlocks, blk, 0, stream>>>(dst, degcnt, E);
    k_scan_all<<<1, dim3(1024), 0, stream>>>(degcnt, dinv, row_start, cursor);
    k_fill<<<edgeBlocks, blk, 0, stream>>>(src, dst, cursor, csrs, E);
    k_prep<<<n8blk + 512, blk, 0, stream>>>(x, xb, n8blk, W1, W2, Wt1, Wt2);

    // ---- layer 1 ----
    k_gemm_bf16<<<gemmGrid, blk, 0, stream>>>(xb, Wt1, dinv, hs);
    k_agg_bn<<<aggBlocks, blk, 0, stream>>>(hs, csrs, row_start, dinv, b1, aggb, bn1sum, bn1sq);
    k_bn_apply_b<<<vec4Blocks, blk, 0, stream>>>(aggb, bn1sum, bn1sq, g1, be1, xb);

    // ---- layer 2 ----
    k_gemm_bf16<<<gemmGrid, blk, 0, stream>>>(xb, Wt2, dinv, hs);
    k_agg_bn<<<aggBlocks, blk, 0, stream>>>(hs, csrs, row_start, dinv, b2, aggb, bn2sum, bn2sq);
    k_bn_pool<<<N_GRAPHS * 16, blk, 0, stream>>>(aggb, bn2sum, bn2sq, g2, be2, pooled);

    // ---- head ----
    k_head<<<N_GRAPHS, blk, 0, stream>>>(pooled, W_ih, b_ih, b_hh, W_fc, b_fc, out);
}

// Round 8
// 319.337 us; speedup vs baseline: 1.4071x; 1.4071x over previous
//
#include <hip/hip_runtime.h>
#include <math.h>

#define N_NODES 32768
#define N_FEAT 256
#define HID 256
#define N_GRAPHS 64
#define NPG 512
#define N_CLASSES 4
#define BN_EPS 1e-5f

typedef __attribute__((ext_vector_type(8))) short bf16x8;
typedef __attribute__((ext_vector_type(4))) float f32x4;

__device__ __forceinline__ ushort f2b(float f) {
    union { float f; uint u; } v; v.f = f;
    uint u = v.u;
    return (ushort)((u + 0x7FFFu + ((u >> 16) & 1u)) >> 16);   // RNE
}
__device__ __forceinline__ float bflo(uint u) {
    union { uint u; float f; } v; v.u = u << 16;
    return v.f;
}
__device__ __forceinline__ float bfhi(uint u) {
    union { uint u; float f; } v; v.u = u & 0xFFFF0000u;
    return v.f;
}

// ---------------- degree (int) ----------------
__global__ void k_count(const int* __restrict__ dst, int* __restrict__ degcnt, int E) {
    int e = blockIdx.x * 256 + threadIdx.x;
    if (e < E) atomicAdd(&degcnt[dst[e]], 1);
}

// single block (1024 thr): scan degcnt -> row_start/cursor (+sentinel), dinv = rsqrt(cnt+1)
__global__ __launch_bounds__(1024) void k_scan_all(const int* __restrict__ degcnt,
                                                   float* __restrict__ dinv,
                                                   int* __restrict__ row_start,
                                                   int* __restrict__ cursor) {
    __shared__ int wsum[16];
    int t = threadIdx.x;
    int base = t * 32;
    int s = 0;
#pragma unroll
    for (int i = 0; i < 32; ++i) s += degcnt[base + i];
    int lane = t & 63, w = t >> 6;
    int v = s;
    for (int off = 1; off < 64; off <<= 1) {
        int u = __shfl_up(v, off);
        if (lane >= off) v += u;
    }
    if (lane == 63) wsum[w] = v;
    __syncthreads();
    if (t < 16) {
        int x = wsum[t];
        for (int off = 1; off < 16; off <<= 1) {
            int u = __shfl_up(x, off, 16);
            if (t >= off) x += u;
        }
        wsum[t] = x;
    }
    __syncthreads();
    int run = ((w > 0) ? wsum[w - 1] : 0) + v - s;
    for (int i = 0; i < 32; ++i) {
        int n = base + i;
        int c = degcnt[n];
        row_start[n] = run;
        cursor[n] = run;
        dinv[n] = rsqrtf((float)(c + 1));
        run += c;
    }
    if (t == 0) row_start[N_NODES] = wsum[15];   // sentinel = E
}

// fill CSR with src only
__global__ void k_fill(const int* __restrict__ src, const int* __restrict__ dst,
                       int* __restrict__ cursor, uint* __restrict__ csrs, int E) {
    int e = blockIdx.x * 256 + threadIdx.x;
    if (e >= E) return;
    int d = dst[e];
    int pos = atomicAdd(&cursor[d], 1);
    csrs[pos] = (uint)src[e];
}

// ---------------- prep: x->bf16 + W transpose ----------------
__global__ void k_prep(const float* __restrict__ x, ushort* __restrict__ xb, int n8blk,
                       const float* __restrict__ W1, const float* __restrict__ W2,
                       ushort* __restrict__ Wt1, ushort* __restrict__ Wt2) {
    int b = blockIdx.x;
    if (b < n8blk) {
        int i = b * 256 + threadIdx.x;
        float4 v0 = *(const float4*)(x + (size_t)i * 8);
        float4 v1 = *(const float4*)(x + (size_t)i * 8 + 4);
        uint4 o;
        o.x = (uint)f2b(v0.x) | ((uint)f2b(v0.y) << 16);
        o.y = (uint)f2b(v0.z) | ((uint)f2b(v0.w) << 16);
        o.z = (uint)f2b(v1.x) | ((uint)f2b(v1.y) << 16);
        o.w = (uint)f2b(v1.z) | ((uint)f2b(v1.w) << 16);
        *(uint4*)(xb + (size_t)i * 8) = o;
    } else {
        int wb = b - n8blk;
        const float* W = (wb < 256) ? W1 : W2;
        ushort* Wt = (wb < 256) ? Wt1 : Wt2;
        int n = wb & 255;
        int k = threadIdx.x;
        Wt[n * 256 + k] = f2b(W[k * 256 + n]);
    }
}

// ---------------- bf16 MFMA GEMM: hs[row][256] = dinv[row] * (A @ Bt^T) ----------------
__global__ __launch_bounds__(256) void k_gemm_bf16(const ushort* __restrict__ A,
                                                   const ushort* __restrict__ Bt,
                                                   const float* __restrict__ dinv,
                                                   ushort* __restrict__ hs) {
    int wid = threadIdx.x >> 6;
    int lane = threadIdx.x & 63;
    int m0 = blockIdx.y * 256 + wid * 64;
    int n0 = blockIdx.x * 64;
    int r = lane & 15;
    int ko = (lane >> 4) * 8;

    const ushort* Ab = A + (size_t)(m0 + r) * 256 + ko;
    const ushort* Bb = Bt + (size_t)(n0 + r) * 256 + ko;

    f32x4 acc[4][4] = {};
#pragma unroll
    for (int ks = 0; ks < 8; ++ks) {
        bf16x8 a[4], b[4];
#pragma unroll
        for (int i = 0; i < 4; ++i) {
            a[i] = *(const bf16x8*)(Ab + i * (16 * 256) + ks * 32);
            b[i] = *(const bf16x8*)(Bb + i * (16 * 256) + ks * 32);
        }
#pragma unroll
        for (int i = 0; i < 4; ++i)
#pragma unroll
            for (int j = 0; j < 4; ++j)
                acc[i][j] = __builtin_amdgcn_mfma_f32_16x16x32_bf16(a[i], b[j], acc[i][j], 0, 0, 0);
    }

    int rr = (lane >> 4) * 4;   // C/D: row=(lane>>4)*4+reg, col=lane&15
    int cc = lane & 15;
#pragma unroll
    for (int i = 0; i < 4; ++i) {
        int row = m0 + i * 16 + rr;
#pragma unroll
        for (int r2 = 0; r2 < 4; ++r2) {
            float dv = dinv[row + r2];
#pragma unroll
            for (int j = 0; j < 4; ++j) {
                int col = n0 + j * 16 + cc;
                hs[(size_t)(row + r2) * 256 + col] = f2b(acc[i][j][r2] * dv);
            }
        }
    }
}

// ---------------- CSR aggregate (full-row gather, 1 wave = 1 node) ----------------
// hs[node][256] = dinv-prescaled h'. agg[n] = dv*(sum h'[src] + h'[n]) + bias.
// 4 waves/block, 8192 blocks; lane owns feature quad foff = lane*4 (uint2 = 4 bf16).
__global__ __launch_bounds__(256) void k_agg(const ushort* __restrict__ hs,
                                             const uint* __restrict__ csrs,
                                             const int* __restrict__ row_start,
                                             const float* __restrict__ dinv,
                                             const float* __restrict__ bias,
                                             ushort* __restrict__ aggb) {
    int wid = threadIdx.x >> 6;
    int lane = threadIdx.x & 63;
    int foff = lane * 4;
    int n = blockIdx.x * 4 + wid;

    float dv = dinv[n];
    int base = row_start[n];
    int cnt = row_start[n + 1] - base;

    uint2 hv = *(const uint2*)(hs + (size_t)n * 256 + foff);
    float a0 = bflo(hv.x), a1 = bfhi(hv.x), a2 = bflo(hv.y), a3 = bfhi(hv.y);

    int j = 0;
    for (; j + 8 <= cnt; j += 8) {
        uint s0 = csrs[base + j + 0];
        uint s1 = csrs[base + j + 1];
        uint s2 = csrs[base + j + 2];
        uint s3 = csrs[base + j + 3];
        uint s4 = csrs[base + j + 4];
        uint s5 = csrs[base + j + 5];
        uint s6 = csrs[base + j + 6];
        uint s7 = csrs[base + j + 7];
        uint2 h0 = *(const uint2*)(hs + (size_t)s0 * 256 + foff);
        uint2 h1 = *(const uint2*)(hs + (size_t)s1 * 256 + foff);
        uint2 h2 = *(const uint2*)(hs + (size_t)s2 * 256 + foff);
        uint2 h3 = *(const uint2*)(hs + (size_t)s3 * 256 + foff);
        uint2 h4 = *(const uint2*)(hs + (size_t)s4 * 256 + foff);
        uint2 h5 = *(const uint2*)(hs + (size_t)s5 * 256 + foff);
        uint2 h6 = *(const uint2*)(hs + (size_t)s6 * 256 + foff);
        uint2 h7 = *(const uint2*)(hs + (size_t)s7 * 256 + foff);
        a0 += bflo(h0.x) + bflo(h1.x) + bflo(h2.x) + bflo(h3.x)
            + bflo(h4.x) + bflo(h5.x) + bflo(h6.x) + bflo(h7.x);
        a1 += bfhi(h0.x) + bfhi(h1.x) + bfhi(h2.x) + bfhi(h3.x)
            + bfhi(h4.x) + bfhi(h5.x) + bfhi(h6.x) + bfhi(h7.x);
        a2 += bflo(h0.y) + bflo(h1.y) + bflo(h2.y) + bflo(h3.y)
            + bflo(h4.y) + bflo(h5.y) + bflo(h6.y) + bflo(h7.y);
        a3 += bfhi(h0.y) + bfhi(h1.y) + bfhi(h2.y) + bfhi(h3.y)
            + bfhi(h4.y) + bfhi(h5.y) + bfhi(h6.y) + bfhi(h7.y);
    }
    for (; j + 2 <= cnt; j += 2) {
        uint s0 = csrs[base + j + 0];
        uint s1 = csrs[base + j + 1];
        uint2 h0 = *(const uint2*)(hs + (size_t)s0 * 256 + foff);
        uint2 h1 = *(const uint2*)(hs + (size_t)s1 * 256 + foff);
        a0 += bflo(h0.x) + bflo(h1.x);
        a1 += bfhi(h0.x) + bfhi(h1.x);
        a2 += bflo(h0.y) + bflo(h1.y);
        a3 += bfhi(h0.y) + bfhi(h1.y);
    }
    if (j < cnt) {
        uint s0 = csrs[base + j];
        uint2 h0 = *(const uint2*)(hs + (size_t)s0 * 256 + foff);
        a0 += bflo(h0.x); a1 += bfhi(h0.x);
        a2 += bflo(h0.y); a3 += bfhi(h0.y);
    }

    float4 bv = *(const float4*)&bias[foff];
    ushort4 ov;
    ov.x = f2b(a0 * dv + bv.x);
    ov.y = f2b(a1 * dv + bv.y);
    ov.z = f2b(a2 * dv + bv.z);
    ov.w = f2b(a3 * dv + bv.w);
    *(ushort4*)(aggb + (size_t)n * HID + foff) = ov;
}

// ---------------- BN stats over bf16 agg ----------------
__global__ __launch_bounds__(256) void k_bn_stats_b(const ushort* __restrict__ aggb,
                                                    float* __restrict__ bnsum,
                                                    float* __restrict__ bnsq) {
    int f = threadIdx.x;
    int r0 = blockIdx.x * 32;
    float s = 0.0f, q = 0.0f;
#pragma unroll 4
    for (int r = 0; r < 32; ++r) {
        float v = bflo((uint)aggb[(size_t)(r0 + r) * HID + f]);
        s += v;
        q += v * v;
    }
    atomicAdd(&bnsum[f], s);
    atomicAdd(&bnsq[f], q);
}

// ---------------- BN apply (layer1): aggb bf16 -> bf16 xb ----------------
__global__ void k_bn_apply_b(const ushort* __restrict__ x, const float* __restrict__ bnsum,
                             const float* __restrict__ bnsq, const float* __restrict__ gamma,
                             const float* __restrict__ beta, ushort* __restrict__ out) {
    int i = blockIdx.x * 256 + threadIdx.x;   // 4-feat groups
    if (i >= N_NODES * HID / 4) return;
    int f = (i & 63) * 4;
    const float invN = 1.0f / (float)N_NODES;
    uint2 v = *(const uint2*)(x + (size_t)i * 4);
    float vv[4] = {bflo(v.x), bfhi(v.x), bflo(v.y), bfhi(v.y)};
    float r[4];
#pragma unroll
    for (int qq = 0; qq < 4; ++qq) {
        float mean = bnsum[f + qq] * invN;
        float var = bnsq[f + qq] * invN - mean * mean;
        float t = (vv[qq] - mean) * rsqrtf(var + BN_EPS) * gamma[f + qq] + beta[f + qq];
        r[qq] = t > 0.0f ? t : 0.0f;
    }
    uint2 o;
    o.x = (uint)f2b(r[0]) | ((uint)f2b(r[1]) << 16);
    o.y = (uint)f2b(r[2]) | ((uint)f2b(r[3]) << 16);
    *(uint2*)(out + (size_t)i * 4) = o;
}

// ---------------- BN apply (layer2) + mean-pool accumulate (bf16 in) ----------------
__global__ __launch_bounds__(256) void k_bn_pool(const ushort* __restrict__ aggb,
                                                 const float* __restrict__ bnsum,
                                                 const float* __restrict__ bnsq,
                                                 const float* __restrict__ gamma,
                                                 const float* __restrict__ beta,
                                                 float* __restrict__ pooled) {
    int g = blockIdx.x >> 4;
    int blk = blockIdx.x & 15;
    int f = threadIdx.x;
    const float invN = 1.0f / (float)N_NODES;
    float mean = bnsum[f] * invN;
    float var = bnsq[f] * invN - mean * mean;
    float sc = rsqrtf(var + BN_EPS) * gamma[f];
    float sh = beta[f] - mean * sc;
    int r0 = g * NPG + blk * 32;
    float s = 0.0f;
#pragma unroll 4
    for (int r = 0; r < 32; ++r) {
        float v = bflo((uint)aggb[(size_t)(r0 + r) * HID + f]) * sc + sh;
        s += v > 0.0f ? v : 0.0f;
    }
    atomicAdd(&pooled[g * HID + f], s);
}

// ---------------- LSTM cell + FC + log_softmax ----------------
__global__ __launch_bounds__(256) void k_head(const float* __restrict__ pooled,
                                              const float* __restrict__ W_ih,
                                              const float* __restrict__ b_ih,
                                              const float* __restrict__ b_hh,
                                              const float* __restrict__ W_fc,
                                              const float* __restrict__ b_fc,
                                              float* __restrict__ out) {
    __shared__ float p[HID];
    __shared__ float lsum[N_CLASSES][256];
    __shared__ float logits[N_CLASSES];
    int g = blockIdx.x, j = threadIdx.x;
    p[j] = pooled[g * HID + j] * (1.0f / (float)NPG);
    __syncthreads();

    float gi = 0.f, gf = 0.f, gg = 0.f, go = 0.f;
#pragma unroll 4
    for (int k = 0; k < HID; ++k) {
        float pk = p[k];
        const float* w = &W_ih[(size_t)k * (4 * HID) + j];
        gi += pk * w[0];
        gf += pk * w[HID];
        gg += pk * w[2 * HID];
        go += pk * w[3 * HID];
    }
    gi += b_ih[j] + b_hh[j];
    gf += b_ih[HID + j] + b_hh[HID + j];
    gg += b_ih[2 * HID + j] + b_hh[2 * HID + j];
    go += b_ih[3 * HID + j] + b_hh[3 * HID + j];
    (void)gf;  // c0 == 0

    float si = 1.f / (1.f + expf(-gi));
    float so = 1.f / (1.f + expf(-go));
    float c1 = si * tanhf(gg);
    float h1 = so * tanhf(c1);

    out[N_GRAPHS * N_CLASSES + g * HID + j] = h1;
    out[N_GRAPHS * N_CLASSES + N_GRAPHS * HID + g * HID + j] = c1;

#pragma unroll
    for (int c = 0; c < N_CLASSES; ++c)
        lsum[c][j] = h1 * W_fc[j * N_CLASSES + c];
    __syncthreads();
    for (int s = 128; s > 0; s >>= 1) {
        if (j < s) {
#pragma unroll
            for (int c = 0; c < N_CLASSES; ++c)
                lsum[c][j] += lsum[c][j + s];
        }
        __syncthreads();
    }
    if (j < N_CLASSES) logits[j] = lsum[j][0] + b_fc[j];
    __syncthreads();
    if (j < N_CLASSES) {
        float m = fmaxf(fmaxf(logits[0], logits[1]), fmaxf(logits[2], logits[3]));
        float lse = m + logf(expf(logits[0] - m) + expf(logits[1] - m) +
                             expf(logits[2] - m) + expf(logits[3] - m));
        out[g * N_CLASSES + j] = logits[j] - lse;
    }
}

extern "C" void kernel_launch(void* const* d_in, const int* in_sizes, int n_in,
                              void* d_out, int out_size, void* d_ws, size_t ws_size,
                              hipStream_t stream) {
    const float* x    = (const float*)d_in[0];
    const int*   ei   = (const int*)d_in[1];
    const float* W1   = (const float*)d_in[3];
    const float* b1   = (const float*)d_in[4];
    const float* g1   = (const float*)d_in[5];
    const float* be1  = (const float*)d_in[6];
    const float* W2   = (const float*)d_in[7];
    const float* b2   = (const float*)d_in[8];
    const float* g2   = (const float*)d_in[9];
    const float* be2  = (const float*)d_in[10];
    const float* W_ih = (const float*)d_in[11];
    const float* b_ih = (const float*)d_in[13];
    const float* b_hh = (const float*)d_in[14];
    const float* W_fc = (const float*)d_in[15];
    const float* b_fc = (const float*)d_in[16];
    float* out = (float*)d_out;

    int E = in_sizes[1] / 2;
    const int* src = ei;
    const int* dst = ei + E;

    const size_t MAT = (size_t)N_NODES * HID;   // 8388608
    ushort* aggb = (ushort*)d_ws;               // bf16 aggregate output
    ushort* xb   = aggb + MAT;
    ushort* hs   = xb + MAT;                    // node-major prescaled GEMM output
    ushort* Wt1  = hs + MAT;
    ushort* Wt2  = Wt1 + 65536;
    float*  dinv = (float*)(Wt2 + 65536);
    int*    row_start = (int*)(dinv + N_NODES);           // N_NODES+1 (sentinel)
    int*    cursor    = row_start + N_NODES + 1;
    uint*   csrs      = (uint*)(cursor + N_NODES);        // E uints
    // zero-init region (one memset): degcnt + bn sums + pooled
    int*    degcnt = (int*)(csrs + E);
    float*  bn1sum = (float*)(degcnt + N_NODES);
    float*  bn1sq  = bn1sum + HID;
    float*  bn2sum = bn1sq + HID;
    float*  bn2sq  = bn2sum + HID;
    float*  pooled = bn2sq + HID;
    size_t zeroBytes = (size_t)N_NODES * 4 + 4 * HID * 4 + (size_t)N_GRAPHS * HID * 4;

    dim3 blk(256);
    int edgeBlocks = (E + 255) / 256;
    int n8blk = (int)(MAT / 8 / 256);           // 4096
    int vec4Blocks = (int)(MAT / 4 / 256);      // 8192
    int aggBlocks = N_NODES / 4;                // 8192
    dim3 gemmGrid(HID / 64, N_NODES / 256);

    hipMemsetAsync(degcnt, 0, zeroBytes, stream);

    // graph structure + prep
    k_count<<<edgeBlocks, blk, 0, stream>>>(dst, degcnt, E);
    k_scan_all<<<1, dim3(1024), 0, stream>>>(degcnt, dinv, row_start, cursor);
    k_fill<<<edgeBlocks, blk, 0, stream>>>(src, dst, cursor, csrs, E);
    k_prep<<<n8blk + 512, blk, 0, stream>>>(x, xb, n8blk, W1, W2, Wt1, Wt2);

    // ---- layer 1 ----
    k_gemm_bf16<<<gemmGrid, blk, 0, stream>>>(xb, Wt1, dinv, hs);
    k_agg<<<aggBlocks, blk, 0, stream>>>(hs, csrs, row_start, dinv, b1, aggb);
    k_bn_stats_b<<<N_NODES / 32, blk, 0, stream>>>(aggb, bn1sum, bn1sq);
    k_bn_apply_b<<<vec4Blocks, blk, 0, stream>>>(aggb, bn1sum, bn1sq, g1, be1, xb);

    // ---- layer 2 ----
    k_gemm_bf16<<<gemmGrid, blk, 0, stream>>>(xb, Wt2, dinv, hs);
    k_agg<<<aggBlocks, blk, 0, stream>>>(hs, csrs, row_start, dinv, b2, aggb);
    k_bn_stats_b<<<N_NODES / 32, blk, 0, stream>>>(aggb, bn2sum, bn2sq);
    k_bn_pool<<<N_GRAPHS * 16, blk, 0, stream>>>(aggb, bn2sum, bn2sq, g2, be2, pooled);

    // ---- head ----
    k_head<<<N_GRAPHS, blk, 0, stream>>>(pooled, W_ih, b_ih, b_hh, W_fc, b_fc, out);
}